// Round 7
// baseline (327.953 us; speedup 1.0000x reference)
//
#include <hip/hip_runtime.h>
#include <hip/hip_bf16.h>
#include <math.h>

#define NV 50000
#define NE 600000
#define NM 100000
#define KIN 256
#define HCC 256
#define NHH 8

// chunked LDS histogram geometry
#define NCH 32                 // chunks
#define CHUNK 18750            // NE / NCH
#define KRANGE 25000           // keys per LDS pass (u16-packed: 12500 u32 = 50KB)
#define HIST_B (NCH * 6)       // passes 0-3: e-side (4x25K=100K), 4-5: v-side (2x25K=50K)
#define CSCAN_B 74             // ceil((NM/2 + NV/2)/1024)

// parallel scan geometry: 4096 elements per block (1024 threads x int4)
#define SCAN_NB0 25   // ceil((NM+1)/4096)
#define SCAN_NB1 13   // ceil((NV+1)/4096)

#define CNT_B 2344    // ceil(NE/256) incidence blocks (fill kernels)
#define GEMM_RG 784   // row-groups launched (782 real + 2 spare for the 8-row remap)
#define GEMM_B (GEMM_RG * 4)

typedef unsigned int u32;
typedef unsigned short u16;
typedef _Float16 f16;
typedef _Float16 v8h __attribute__((ext_vector_type(8)));
typedef _Float16 v4h __attribute__((ext_vector_type(4)));
typedef float v4f __attribute__((ext_vector_type(4)));

// ---- chunked LDS histogram + rank (atomic-free at global scope) ----
// Rounds 3-5 proved global atomics run at a fixed shared-pipe rate (~12.5 G/s)
// regardless of XCD locality or scope -> eliminate them. Each block histograms
// one chunk of 18750 incidences for one 25K-key range entirely in LDS
// (u16-packed pairs in u32; per-(chunk,key) count <= 18750 fits u16; real
// degrees are ~tens so no cross-half carry). LDS atomicAdd return = rank.
__global__ __launch_bounds__(256) void k_hist(const int* __restrict__ vertex,
                                              const int* __restrict__ edges,
                                              u16* __restrict__ r_e,
                                              u16* __restrict__ r_v,
                                              u16* __restrict__ Ce,
                                              u16* __restrict__ Cv) {
    __shared__ __align__(16) u32 hist[KRANGE / 2];   // 50KB
    const int bid = blockIdx.x;
    const int t = threadIdx.x;
    const int pass = bid >> 5;            // 0..5
    const int chunk = bid & (NCH - 1);
    const bool eside = pass < 4;
    const int kbase = (eside ? pass : pass - 4) * KRANGE;
    const int* keys = eside ? edges : vertex;
    u16* rout = eside ? r_e : r_v;
    u16* crow = eside ? (Ce + (size_t)chunk * NM) : (Cv + (size_t)chunk * NV);

    uint4* h4 = (uint4*)hist;
    for (int j = t; j < KRANGE / 8; j += 256) h4[j] = make_uint4(0u, 0u, 0u, 0u);
    __syncthreads();

    const int i0 = chunk * CHUNK;
    for (int i = i0 + t; i < i0 + CHUNK; i += 256) {
        int k = keys[i] - kbase;
        if ((u32)k < (u32)KRANGE) {
            int sh = (k & 1) << 4;
            u32 old = atomicAdd(&hist[k >> 1], 1u << sh);
            rout[i] = (u16)(old >> sh);
        }
    }
    __syncthreads();

    uint4* d4 = (uint4*)(crow + kbase);   // 16B-aligned: row strides & kbase*2 are %16==0
    for (int j = t; j < KRANGE / 8; j += 256) d4[j] = h4[j];
}

// ---- column scan over chunks: C[c][k] -> exclusive prefix over c; totals out ----
// Packed-u32 arithmetic on u16 pairs (no carry: per-key totals <= ~40).
__global__ __launch_bounds__(1024) void k_cscan(u16* __restrict__ Ce,
                                                u16* __restrict__ Cv,
                                                int* __restrict__ e_start,
                                                int* __restrict__ v_start) {
    int tid = blockIdx.x * 1024 + threadIdx.x;
    u32* mat;
    int* outp;
    int col, ncol;
    if (tid < NM / 2)               { mat = (u32*)Ce; outp = e_start; col = tid;          ncol = NM / 2; }
    else if (tid < NM / 2 + NV / 2) { mat = (u32*)Cv; outp = v_start; col = tid - NM / 2; ncol = NV / 2; }
    else return;
    u32 s = 0;
    u32* p = mat + col;
    for (int c = 0; c < NCH; ++c) {
        u32 o = *p;
        *p = s;
        s += o;
        p += ncol;
    }
    outp[2 * col + 1] = (int)(s & 0xffffu);
    outp[2 * col + 2] = (int)(s >> 16);
}

// ---- fp16 MFMA GEMM: X0 = f16(X @ W), 64x64 tiles ----
// XCD remap: the 4 column-tiles of one row-group satisfy g&7 == rg&7 -> same XCD
// under round-robin dispatch -> X fetched from HBM once (FETCH 102->28MB, round 3).
__global__ __launch_bounds__(256) void k_gemm(const float* __restrict__ X,
                                              const float* __restrict__ W,
                                              f16* __restrict__ X0) {
    __shared__ __align__(16) f16 sA[64][72];
    __shared__ __align__(16) f16 sB[64][72];
    const int g = blockIdx.x;
    const int rg = (g >> 5) * 8 + (g & 7);     // row-group
    const int cg = (g >> 3) & 3;               // column-group
    if (rg >= (NV + 63) / 64) return;
    const int t = threadIdx.x;
    const int r0 = rg * 64;
    const int c0 = cg * 64;
    const int wave = t >> 6;
    const int lane = t & 63;
    const int quad = lane >> 4;
    const int l16 = lane & 15;
    const int wr = wave & 1;
    const int wc = wave >> 1;

    v4f acc[2][2] = {{{0.f,0.f,0.f,0.f},{0.f,0.f,0.f,0.f}},
                     {{0.f,0.f,0.f,0.f},{0.f,0.f,0.f,0.f}}};

    for (int kc = 0; kc < KIN; kc += 64) {
        __syncthreads();
        #pragma unroll
        for (int i = 0; i < 4; ++i) {
            int lin = i * 256 + t;
            int row = lin >> 4;
            int k = (lin & 15) * 4;
            int gr = r0 + row;
            float4 x = make_float4(0.f, 0.f, 0.f, 0.f);
            if (gr < NV) x = *(const float4*)(X + (size_t)gr * KIN + kc + k);
            v4h hv = { (f16)x.x, (f16)x.y, (f16)x.z, (f16)x.w };
            *(v4h*)&sA[row][k] = hv;
        }
        #pragma unroll
        for (int i = 0; i < 4; ++i) {
            int lin = i * 256 + t;
            int k = lin >> 4;
            int n = (lin & 15) * 4;
            float4 b = *(const float4*)(W + (size_t)(kc + k) * HCC + c0 + n);
            sB[n + 0][k] = (f16)b.x;
            sB[n + 1][k] = (f16)b.y;
            sB[n + 2][k] = (f16)b.z;
            sB[n + 3][k] = (f16)b.w;
        }
        __syncthreads();
        #pragma unroll
        for (int ks = 0; ks < 2; ++ks) {
            const int kb = ks * 32 + quad * 8;
            v8h a[2], b[2];
            #pragma unroll
            for (int rf = 0; rf < 2; ++rf)
                a[rf] = *(const v8h*)&sA[wr * 32 + rf * 16 + l16][kb];
            #pragma unroll
            for (int cf = 0; cf < 2; ++cf)
                b[cf] = *(const v8h*)&sB[wc * 32 + cf * 16 + l16][kb];
            #pragma unroll
            for (int rf = 0; rf < 2; ++rf)
                #pragma unroll
                for (int cf = 0; cf < 2; ++cf)
                    acc[rf][cf] = __builtin_amdgcn_mfma_f32_16x16x32_f16(a[rf], b[cf], acc[rf][cf], 0, 0, 0);
        }
    }
    #pragma unroll
    for (int rf = 0; rf < 2; ++rf)
        #pragma unroll
        for (int cf = 0; cf < 2; ++cf)
            #pragma unroll
            for (int r = 0; r < 4; ++r) {
                int grow = r0 + wr * 32 + rf * 16 + quad * 4 + r;
                if (grow < NV)
                    X0[(size_t)grow * HCC + c0 + wc * 32 + cf * 16 + l16] = (f16)acc[rf][cf][r];
            }
}

// ---------------- parallel scan pass 1: per-block inclusive scan + block sums ------
__global__ __launch_bounds__(1024) void k_scan_blk(int* __restrict__ a0,
                                                   int* __restrict__ a1,
                                                   int* __restrict__ bsum) {
    const int b = blockIdx.x;
    int* a;
    int n, base;
    if (b < SCAN_NB0) { a = a0; n = NM + 1; base = b * 4096; }
    else              { a = a1; n = NV + 1; base = (b - SCAN_NB0) * 4096; }
    const int t = threadIdx.x;
    const int lane = t & 63, w = t >> 6;
    const int i = base + t * 4;
    int4 v = make_int4(0, 0, 0, 0);
    if (i + 3 < n) v = *(const int4*)(a + i);
    else if (i < n) {
        v.x = a[i];
        if (i + 1 < n) v.y = a[i + 1];
        if (i + 2 < n) v.z = a[i + 2];
    }
    v.y += v.x; v.z += v.y; v.w += v.z;
    int s = v.w;
    #pragma unroll
    for (int d = 1; d < 64; d <<= 1) {
        int x = __shfl_up(s, d, 64);
        if (lane >= d) s += x;
    }
    __shared__ int partials[16];
    __shared__ int woff[16];
    if (lane == 63) partials[w] = s;
    __syncthreads();
    if (t < 16) {
        int p = partials[t];
        int ps = p;
        #pragma unroll
        for (int d = 1; d < 16; d <<= 1) {
            int x = __shfl_up(ps, d, 64);
            if (t >= d) ps += x;
        }
        woff[t] = ps - p;
        if (t == 15) bsum[b] = ps;
    }
    __syncthreads();
    const int add = (s - v.w) + woff[w];
    v.x += add; v.y += add; v.z += add; v.w += add;
    if (i + 3 < n) *(int4*)(a + i) = v;
    else if (i < n) {
        a[i] = v.x;
        if (i + 1 < n) a[i + 1] = v.y;
        if (i + 2 < n) a[i + 2] = v.z;
    }
}

// ---------------- parallel scan pass 2: add block offsets ----------------
__global__ __launch_bounds__(1024) void k_scan_add(int* __restrict__ a0,
                                                   int* __restrict__ a1,
                                                   const int* __restrict__ bsum) {
    const int b = blockIdx.x;
    int* a;
    int n, bs0, blocal;
    if (b < SCAN_NB0) { a = a0; n = NM + 1; bs0 = 0;        blocal = b; }
    else              { a = a1; n = NV + 1; bs0 = SCAN_NB0; blocal = b - SCAN_NB0; }
    const int t = threadIdx.x;
    const int lane = t & 63;
    int x = (lane < blocal) ? bsum[bs0 + lane] : 0;
    #pragma unroll
    for (int d = 1; d < 64; d <<= 1) x += __shfl_xor(x, d, 64);
    const int off = x;
    const int i = blocal * 4096 + t * 4;
    if (i + 3 < n) {
        int4 v = *(const int4*)(a + i);
        v.x += off; v.y += off; v.z += off; v.w += off;
        *(int4*)(a + i) = v;
    } else if (i < n) {
        a[i] += off;
        if (i + 1 < n) a[i + 1] += off;
        if (i + 2 < n) a[i + 2] += off;
    }
}

// ---------------- e-side CSR fill: atomic-free ----------------
// pos = segment start + chunk offset (from cscan) + rank-within-(chunk,segment)
__global__ __launch_bounds__(256) void k_efill(const int* __restrict__ vertex,
                                               const int* __restrict__ edges,
                                               const u16* __restrict__ r_e,
                                               const int* __restrict__ e_start,
                                               const u16* __restrict__ Ce,
                                               int* __restrict__ e_list) {
    int i = blockIdx.x * 256 + threadIdx.x;
    if (i >= NE) return;
    int m = edges[i];
    int chunk = i / CHUNK;
    int pos = e_start[m] + (int)Ce[(size_t)chunk * NM + m] + (int)r_e[i];
    e_list[pos] = vertex[i];
}

// ---- fused: v-side CSR fill (atomic-free) blocks || per-hyperedge gather blocks ----
__global__ __launch_bounds__(256) void k_vfill_egather(const int* __restrict__ vertex,
                                                       const int* __restrict__ edges,
                                                       const u16* __restrict__ r_v,
                                                       const int* __restrict__ v_start,
                                                       const u16* __restrict__ Cv,
                                                       int* __restrict__ v_list,
                                                       const int* __restrict__ e_start,
                                                       const int* __restrict__ e_list,
                                                       const f16* __restrict__ X0,
                                                       const float* __restrict__ att,
                                                       f16* __restrict__ Xe,
                                                       float* __restrict__ alpha_e) {
    const int bid = blockIdx.x;
    if (bid < CNT_B) {
        int i = bid * 256 + threadIdx.x;
        if (i < NE) {
            int v = vertex[i];
            int chunk = i / CHUNK;
            int pos = v_start[v] + (int)Cv[(size_t)chunk * NV + v] + (int)r_v[i];
            v_list[pos] = edges[i];
        }
        return;
    }
    int m = (bid - CNT_B) * 4 + (threadIdx.x >> 6);
    int lane = threadIdx.x & 63;
    int s0 = e_start[m], s1 = e_start[m + 1];
    int c = lane * 4;
    float4 acc = make_float4(0.f, 0.f, 0.f, 0.f);
    int i = s0;
    for (; i + 3 < s1; i += 4) {
        int v0 = e_list[i], v1 = e_list[i + 1], v2 = e_list[i + 2], v3 = e_list[i + 3];
        v4h x0 = *(const v4h*)(X0 + (size_t)v0 * HCC + c);
        v4h x1 = *(const v4h*)(X0 + (size_t)v1 * HCC + c);
        v4h x2 = *(const v4h*)(X0 + (size_t)v2 * HCC + c);
        v4h x3 = *(const v4h*)(X0 + (size_t)v3 * HCC + c);
        acc.x += (float)x0[0] + (float)x1[0] + (float)x2[0] + (float)x3[0];
        acc.y += (float)x0[1] + (float)x1[1] + (float)x2[1] + (float)x3[1];
        acc.z += (float)x0[2] + (float)x1[2] + (float)x2[2] + (float)x3[2];
        acc.w += (float)x0[3] + (float)x1[3] + (float)x2[3] + (float)x3[3];
    }
    for (; i < s1; ++i) {
        int v0 = e_list[i];
        v4h x0 = *(const v4h*)(X0 + (size_t)v0 * HCC + c);
        acc.x += (float)x0[0];
        acc.y += (float)x0[1];
        acc.z += (float)x0[2];
        acc.w += (float)x0[3];
    }
    float inv = 1.0f / fmaxf((float)(s1 - s0), 1.0f);
    acc.x *= inv; acc.y *= inv; acc.z *= inv; acc.w *= inv;
    v4h xev = { (f16)acc.x, (f16)acc.y, (f16)acc.z, (f16)acc.w };
    *(v4h*)(Xe + (size_t)m * HCC + c) = xev;
    float4 av = *(const float4*)(att + c);
    float p = acc.x * av.x + acc.y * av.y + acc.z * av.z + acc.w * av.w;
    p += __shfl_xor(p, 1, 64);
    p += __shfl_xor(p, 2, 64);
    p += __shfl_xor(p, 4, 64);
    if ((lane & 7) == 0) alpha_e[m * NHH + (lane >> 3)] = p;
}

// ---------------- per-vertex gather: softmax (no max shift; |alpha|<~2) + GELU ----------
__global__ __launch_bounds__(256) void k_vertex_gather(const int* __restrict__ v_start,
                                                       const int* __restrict__ v_list,
                                                       const f16* __restrict__ Xe,
                                                       const float* __restrict__ alpha_e,
                                                       float* __restrict__ out) {
    int v = blockIdx.x * 4 + (threadIdx.x >> 6);
    int lane = threadIdx.x & 63;
    int s0 = v_start[v], s1 = v_start[v + 1];
    int h = lane >> 3;
    int c = lane * 4;
    float4 acc = make_float4(0.f, 0.f, 0.f, 0.f);
    float se = 0.f;
    int i = s0;
    for (; i + 1 < s1; i += 2) {
        int m0 = v_list[i], m1 = v_list[i + 1];
        float a0 = alpha_e[m0 * NHH + h];
        float a1 = alpha_e[m1 * NHH + h];
        v4h x0 = *(const v4h*)(Xe + (size_t)m0 * HCC + c);
        v4h x1 = *(const v4h*)(Xe + (size_t)m1 * HCC + c);
        a0 = (a0 >= 0.f) ? a0 : 0.2f * a0;
        a1 = (a1 >= 0.f) ? a1 : 0.2f * a1;
        float e0 = __expf(a0);
        float e1 = __expf(a1);
        acc.x += e0 * (float)x0[0] + e1 * (float)x1[0];
        acc.y += e0 * (float)x0[1] + e1 * (float)x1[1];
        acc.z += e0 * (float)x0[2] + e1 * (float)x1[2];
        acc.w += e0 * (float)x0[3] + e1 * (float)x1[3];
        se += e0 + e1;
    }
    if (i < s1) {
        int m0 = v_list[i];
        float a0 = alpha_e[m0 * NHH + h];
        v4h x0 = *(const v4h*)(Xe + (size_t)m0 * HCC + c);
        a0 = (a0 >= 0.f) ? a0 : 0.2f * a0;
        float e0 = __expf(a0);
        acc.x += e0 * (float)x0[0];
        acc.y += e0 * (float)x0[1];
        acc.z += e0 * (float)x0[2];
        acc.w += e0 * (float)x0[3];
        se += e0;
    }
    float inv = 1.0f / (se + 1e-16f);
    float4 o;
    float xx;
    xx = acc.x * inv; o.x = 0.5f * xx * (1.f + erff(xx * 0.70710678118f));
    xx = acc.y * inv; o.y = 0.5f * xx * (1.f + erff(xx * 0.70710678118f));
    xx = acc.z * inv; o.z = 0.5f * xx * (1.f + erff(xx * 0.70710678118f));
    xx = acc.w * inv; o.w = 0.5f * xx * (1.f + erff(xx * 0.70710678118f));
    *(float4*)(out + (size_t)v * HCC + c) = o;
}

extern "C" void kernel_launch(void* const* d_in, const int* in_sizes, int n_in,
                              void* d_out, int out_size, void* d_ws, size_t ws_size,
                              hipStream_t stream) {
    const float* X = (const float*)d_in[0];    // [NV, 256] fp32
    const float* W = (const float*)d_in[1];    // [256, 256] fp32
    const float* att = (const float*)d_in[2];  // [256] fp32
    const int* vertex = (const int*)d_in[3];   // [NE] int32
    const int* edges = (const int*)d_in[4];    // [NE] int32
    float* out = (float*)d_out;                // [NV*256] fp32

    char* ws = (char*)d_ws;
    size_t off = 0;
    #define WS_TAKE(bytes) (ws + off); off += (((size_t)(bytes)) + 15) & ~(size_t)15
    f16* X0 = (f16*)WS_TAKE((size_t)NV * HCC * 2);          // 25.6MB
    f16* Xe = (f16*)WS_TAKE((size_t)NM * HCC * 2);          // 51.2MB
    float* alpha_e = (float*)WS_TAKE((size_t)NM * NHH * 4); // 3.2MB
    // contiguous zeroed region: e_start, v_start (Ce/Cv fully overwritten -> no zero)
    size_t z0 = off;
    int* e_start = (int*)WS_TAKE((size_t)(NM + 1) * 4);
    int* v_start = (int*)WS_TAKE((size_t)(NV + 1) * 4);
    size_t z1 = off;
    int* e_list = (int*)WS_TAKE((size_t)NE * 4);            // 2.4MB
    int* v_list = (int*)WS_TAKE((size_t)NE * 4);            // 2.4MB
    u16* r_e = (u16*)WS_TAKE((size_t)NE * 2);               // 1.2MB rank-in-(chunk,edge)
    u16* r_v = (u16*)WS_TAKE((size_t)NE * 2);               // 1.2MB rank-in-(chunk,vertex)
    u16* Ce = (u16*)WS_TAKE((size_t)NCH * NM * 2);          // 6.4MB chunk-count matrix
    u16* Cv = (u16*)WS_TAKE((size_t)NCH * NV * 2);          // 3.2MB
    int* bsum = (int*)WS_TAKE(64 * 4);                      // 38 used
    #undef WS_TAKE

    hipMemsetAsync(e_start, 0, z1 - z0, stream);

    k_hist<<<HIST_B, 256, 0, stream>>>(vertex, edges, r_e, r_v, Ce, Cv);
    k_cscan<<<CSCAN_B, 1024, 0, stream>>>(Ce, Cv, e_start, v_start);
    k_scan_blk<<<SCAN_NB0 + SCAN_NB1, 1024, 0, stream>>>(e_start, v_start, bsum);
    k_scan_add<<<SCAN_NB0 + SCAN_NB1, 1024, 0, stream>>>(e_start, v_start, bsum);
    k_gemm<<<GEMM_B, 256, 0, stream>>>(X, W, X0);
    k_efill<<<CNT_B, 256, 0, stream>>>(vertex, edges, r_e, e_start, Ce, e_list);
    k_vfill_egather<<<CNT_B + NM / 4, 256, 0, stream>>>(vertex, edges, r_v, v_start, Cv, v_list,
                                                        e_start, e_list, X0, att, Xe, alpha_e);
    k_vertex_gather<<<NV / 4, 256, 0, stream>>>(v_start, v_list, Xe, alpha_e, out);
}